// Round 12
// baseline (748.044 us; speedup 1.0000x reference)
//
#include <hip/hip_runtime.h>
#include <hip/hip_bf16.h>

typedef float f32x4 __attribute__((ext_vector_type(4)));
typedef short bf16x8 __attribute__((ext_vector_type(8)));
typedef unsigned short us8 __attribute__((ext_vector_type(8)));

__device__ __forceinline__ unsigned short f2bf(float f) {
  union { float f; unsigned u; } v; v.f = f;
  return (unsigned short)((v.u + 0x8000u) >> 16);   // round-half-up bf16
}
__device__ __forceinline__ float bf2f(unsigned short u) {
  union { unsigned u; float f; } v; v.u = ((unsigned)u) << 16;
  return v.f;
}

// ---------------------------------------------------------------------------
// Kernel 1: VmatT[b][n][p] (bf16), n = c*16+u*4+v (256), p = pi*64+pj (4096)
// ---------------------------------------------------------------------------
__global__ __launch_bounds__(256) void prep_vmat(const float* __restrict__ x,
                                                 unsigned short* __restrict__ vmatT) {
  int t = blockIdx.x * 256 + threadIdx.x;
  int pc = t & 511;
  int n  = (t >> 9) & 255;
  int b  = t >> 17;
  int c = n >> 4, u = (n >> 2) & 3, v = n & 3;
  int pi = pc >> 3;
  int pj0 = (pc & 7) << 3;
  int row = 2 * pi + u - 1;
  row = row < 0 ? 0 : (row > 127 ? 127 : row);
  const float* xr = x + ((size_t)(b * 16 + c) * 128 + row) * 128;
  us8 o;
#pragma unroll
  for (int e = 0; e < 8; ++e) {
    int col = 2 * (pj0 + e) + v - 1;
    col = col < 0 ? 0 : (col > 127 ? 127 : col);
    o[e] = f2bf(xr[col]);
  }
  *reinterpret_cast<us8*>(vmatT + (size_t)t * 8) = o;
}

// ---------------------------------------------------------------------------
// Kernel 2: A[b][q][n] (bf16) = sum_p scores[b][q][p] * VmatT[b][n][p]
// BARRIER-FREE GEMM. M=4096, N=256, K=4096. 512 blocks x 4 waves; each wave
// independently owns 16 q-rows x all 256 n. NO LDS, NO __syncthreads, NO
// manual waitcnt — waves drift freely, so an HBM tail-latency hit stalls one
// wave, not all eight on the CU (R3..R11 showed the lockstep barrier convoy
// is structure-invariant ~2000 cyc/iter regardless of BK / blocks-per-CU).
//  - A (scores, HBM): per-lane direct MFMA fragment (row l15, k=l16*8),
//    reg-staged 2 K-tiles ahead (rE/rO named sets; CONV extracts BEFORE the
//    reload — R5 lesson). 128-B per row per tile.
//  - B (VmatT, n-major, XCD-pinned L2-resident 2 MB/batch): fragment loaded
//    just-in-time from global: VmatT[(ni*16+l15)*4096 + kp*32 + l16*8],
//    16 B/lane over 16 rows = 16-line coalesced; the block's 8 waves reuse
//    each 16 KB K-tile through L1/L2. L2 budget ~30 us << A's 85 us floor.
//  - compiler does all scheduling/pipelining (its strength; m97 evidence).
//  - K-phase rotation (128 tiles) spreads DRAM pages across blocks.
// ---------------------------------------------------------------------------
__global__ __launch_bounds__(256) void gemm_scores_vmat(
    const float* __restrict__ scores,
    const unsigned short* __restrict__ vmatT,
    unsigned short* __restrict__ Amat) {
  int bid = blockIdx.x;
  int nb = ((bid & 7) << 6) | (bid >> 3);     // batch = XCD id
  int batch = nb >> 6;
  int qb = (nb & 63) << 6;
  const int phase = (bid >> 3) & 127;         // K rotation among 128 tiles

  const int t = threadIdx.x;
  const int lane = t & 63;
  const int wq = t >> 6;                      // wave id = M-quadrant
  const int l15 = lane & 15, l16 = lane >> 4;

  // A: per-lane fragment base (row = qb + wq*16 + l15, k-offset l16*8)
  const float* aLane =
      scores + ((size_t)(batch * 4096 + qb + wq * 16 + l15)) * 4096 + l16 * 8;
  // B: per-lane fragment base (row n = l15 (+ni*16), k-offset l16*8)
  const unsigned short* bLane =
      vmatT + (size_t)batch * 256 * 4096 + (size_t)l15 * 4096 + l16 * 8;

  f32x4 acc[16];
#pragma unroll
  for (int ni = 0; ni < 16; ++ni) acc[ni] = (f32x4){0.f, 0.f, 0.f, 0.f};

  f32x4 rE[2], rO[2];       // two named A reg sets (static indexing)
  bf16x8 fe, fo;

#define LOAD_A(kt, rr)                                                        \
  {                                                                           \
    int kp_ = ((kt) + phase) & 127;                                           \
    const float* ap_ = aLane + (size_t)kp_ * 32;                              \
    rr[0] = *(const f32x4*)(ap_);                                             \
    rr[1] = *(const f32x4*)(ap_ + 4);                                         \
  }
#define CONV(rr, fa)                                                          \
  {                                                                           \
    _Pragma("unroll") for (int e = 0; e < 4; ++e) {                           \
      fa[e] = (short)f2bf(rr[0][e]); fa[e + 4] = (short)f2bf(rr[1][e]);       \
    }                                                                         \
  }
#define TILE(fa, kt)                                                          \
  {                                                                           \
    int kp_ = ((kt) + phase) & 127;                                           \
    const unsigned short* bp_ = bLane + (size_t)kp_ * 32;                     \
    _Pragma("unroll") for (int ni = 0; ni < 16; ++ni) {                       \
      bf16x8 bv = *(const bf16x8*)(bp_ + (size_t)ni * 65536);                 \
      acc[ni] = __builtin_amdgcn_mfma_f32_16x16x32_bf16(fa, bv, acc[ni],      \
                                                        0, 0, 0);             \
    }                                                                         \
  }

  // prologue: A(0)->rE, A(1)->rO
  LOAD_A(0, rE);
  LOAD_A(1, rO);

  // main loop: 128 K-tiles of 32, unrolled x2 (static reg-set roles).
  // No barriers; compiler pipelines loads under MFMAs freely.
  for (int kt = 0; kt < 128; kt += 2) {
    CONV(rE, fe);               // extract BEFORE reload
    LOAD_A(kt + 2, rE);
    TILE(fe, kt);
    CONV(rO, fo);
    LOAD_A(kt + 3, rO);
    TILE(fo, kt + 1);
  }

#undef LOAD_A
#undef CONV
#undef TILE

  // C-write: wave wq owns q-rows qb+wq*16..+15; row=(l16*4+j), col=l15 per ni
  unsigned short* Ao = Amat + ((size_t)(batch * 4096 + qb + wq * 16)) * 256;
#pragma unroll
  for (int ni = 0; ni < 16; ++ni)
#pragma unroll
    for (int j = 0; j < 4; ++j)
      Ao[(size_t)(l16 * 4 + j) * 256 + ni * 16 + l15] = f2bf(acc[ni][j]);
}

// ---------------------------------------------------------------------------
// Kernel 3: out = x + alpha/4 * gathered conv_transpose contributions
// ---------------------------------------------------------------------------
__global__ __launch_bounds__(256) void epilogue_kernel(
    const float* __restrict__ x, const unsigned short* __restrict__ Amat,
    const float* __restrict__ alpha, float* __restrict__ out) {
  int b = blockIdx.x >> 7;
  int h = blockIdx.x & 127;
  int t = threadIdx.x;
  int w = t & 127;
  int cg = t >> 7;

  int ihi = (h + 1) >> 1, u_hi = (h + 1) & 1;
  int jhi = (w + 1) >> 1, v_hi = (w + 1) & 1;
  bool vi_hi = (ihi <= 63), vi_lo = (ihi >= 1);
  bool vj_hi = (jhi <= 63), vj_lo = (jhi >= 1);

  float al = alpha[0] * 0.25f;
  const unsigned short* Ab = Amat + (size_t)b * 4096 * 256;

#pragma unroll
  for (int cc = 0; cc < 8; ++cc) {
    int c = cg * 8 + cc;
    float s = 0.f;
    if (vi_hi) {
      const unsigned short* Ar = Ab + (size_t)(ihi * 64) * 256 + c * 16 + u_hi * 4;
      if (vj_hi) s += bf2f(Ar[jhi * 256 + v_hi]);
      if (vj_lo) s += bf2f(Ar[(jhi - 1) * 256 + v_hi + 2]);
    }
    if (vi_lo) {
      const unsigned short* Ar = Ab + (size_t)((ihi - 1) * 64) * 256 + c * 16 + (u_hi + 2) * 4;
      if (vj_hi) s += bf2f(Ar[jhi * 256 + v_hi]);
      if (vj_lo) s += bf2f(Ar[(jhi - 1) * 256 + v_hi + 2]);
    }
    size_t xi = (((size_t)b * 16 + c) * 128 + h) * 128 + w;
    out[xi] = x[xi] + al * s;
  }
}

extern "C" void kernel_launch(void* const* d_in, const int* in_sizes, int n_in,
                              void* d_out, int out_size, void* d_ws, size_t ws_size,
                              hipStream_t stream) {
  const float* x      = (const float*)d_in[0];
  const float* scores = (const float*)d_in[1];
  const float* alpha  = (const float*)d_in[2];
  float* out = (float*)d_out;

  unsigned short* vmatT = (unsigned short*)d_ws;
  unsigned short* Amat  = (unsigned short*)((char*)d_ws + (size_t)16 * 1024 * 1024);

  prep_vmat<<<4096, 256, 0, stream>>>(x, vmatT);
  gemm_scores_vmat<<<512, 256, 0, stream>>>(scores, vmatT, Amat);
  epilogue_kernel<<<1024, 256, 0, stream>>>(x, Amat, alpha, out);
}

// Round 13
// 172.940 us; speedup vs baseline: 4.3255x; 4.3255x over previous
//
#include <hip/hip_runtime.h>
#include <hip/hip_bf16.h>

typedef float f32x4 __attribute__((ext_vector_type(4)));
typedef short bf16x8 __attribute__((ext_vector_type(8)));
typedef unsigned short us8 __attribute__((ext_vector_type(8)));

__device__ __forceinline__ unsigned short f2bf(float f) {
  union { float f; unsigned u; } v; v.f = f;
  return (unsigned short)((v.u + 0x8000u) >> 16);   // round-half-up bf16
}
__device__ __forceinline__ float bf2f(unsigned short u) {
  union { unsigned u; float f; } v; v.u = ((unsigned)u) << 16;
  return v.f;
}

// ---------------------------------------------------------------------------
// Kernel 1: VmatT[b][n][p] (bf16), n = c*16+u*4+v (256), p = pi*64+pj (4096)
// ---------------------------------------------------------------------------
__global__ __launch_bounds__(256) void prep_vmat(const float* __restrict__ x,
                                                 unsigned short* __restrict__ vmatT) {
  int t = blockIdx.x * 256 + threadIdx.x;
  int pc = t & 511;
  int n  = (t >> 9) & 255;
  int b  = t >> 17;
  int c = n >> 4, u = (n >> 2) & 3, v = n & 3;
  int pi = pc >> 3;
  int pj0 = (pc & 7) << 3;
  int row = 2 * pi + u - 1;
  row = row < 0 ? 0 : (row > 127 ? 127 : row);
  const float* xr = x + ((size_t)(b * 16 + c) * 128 + row) * 128;
  us8 o;
#pragma unroll
  for (int e = 0; e < 8; ++e) {
    int col = 2 * (pj0 + e) + v - 1;
    col = col < 0 ? 0 : (col > 127 ? 127 : col);
    o[e] = f2bf(xr[col]);
  }
  *reinterpret_cast<us8*>(vmatT + (size_t)t * 8) = o;
}

// ---------------------------------------------------------------------------
// Kernel 2: A[b][q][n] (bf16) = sum_p scores[b][q][p] * VmatT[b][n][p]
// DEEP-FIFO GEMM. M=4096, N=256, K=4096. BQ=128 (512 thr, 8 waves M-split:
// wave wq owns rows qb+wq*16..+15 x all 256 n), BK=64, 64 K-tiles.
// LDS = B ring-4 x 32 KB = 128 KB static (R11 precedent), 1 block/CU.
// LITTLE'S-LAW FIX: at every barrier wait, each wave keeps 12 VMEM instr
// in flight (A(kt+3), B(kt+2), A(kt+4) = 12 KB/wave, 96 KB/CU ~ 3x R7):
//  - A: reg-staged 4 tiles ahead (r0..r3, period-4 static unroll); CONV
//    extracts BEFORE the set is overwritten.
//  - B: global_load_lds 16B x4/thread, issued 2 TILES AHEAD into ring-4
//    (written iter j-2, read iter j, prev read iter j-4: 2-barrier gap).
//  - per iter: CONV; STAGE_B(kt+2)[4]; LOAD_A(kt+4)[4]; 32 MFMA;
//    vmcnt(12); barrier.   Drains through B(kt+1) exactly.
//  - B source slot pre-swizzled gs = (c&7)^((c>>3)&7); read same XOR
//    (2-way banks, free). K-phase rotation spreads DRAM pages.
//  - uniform 64 iters; tail wrap loads (&63) kept alive by asm.
// ---------------------------------------------------------------------------
__global__ __launch_bounds__(512, 2) void gemm_scores_vmat(
    const float* __restrict__ scores,
    const unsigned short* __restrict__ vmatT,
    unsigned short* __restrict__ Amat) {
  __shared__ unsigned short ldsB[4][16384];   // 4 x (256 rows x 64 bf16)

  int bid = blockIdx.x;                        // 256 blocks = 1/CU
  int batch = bid & 7;                         // = XCD id
  int qb = (bid >> 3) << 7;                    // 32 q-blocks of 128
  const int phase = ((bid >> 3) * 2) & 63;

  const int t = threadIdx.x;
  const int lane = t & 63;
  const int wq = t >> 6;                       // wave id 0..7 = M slice
  const int l15 = lane & 15, l16 = lane >> 4;

  // A: per-lane fragment base (row = qb + wq*16 + l15, k-offset l16*8)
  const float* aLane =
      scores + ((size_t)(batch * 4096 + qb + wq * 16 + l15)) * 4096 + l16 * 8;
  const unsigned short* Vb = vmatT + (size_t)batch * 256 * 4096;

  // B staging: 2048 chunks of 16B; thread t takes c = t + i*512, i=0..3.
  // row = c>>3, slot = c&7, source slot pre-swizzled gs = slot ^ (row&7).
  const unsigned short* bSrc[4];
#pragma unroll
  for (int i = 0; i < 4; ++i) {
    int c = t + i * 512;
    int gs = (c & 7) ^ ((c >> 3) & 7);
    bSrc[i] = Vb + (size_t)(c >> 3) * 4096 + gs * 8;
  }
  const int pos0 = (l16 ^ (l15 & 7)) << 3;     // swizzled slot, ks=0 (elems)

  f32x4 acc[16];
#pragma unroll
  for (int ni = 0; ni < 16; ++ni) acc[ni] = (f32x4){0.f, 0.f, 0.f, 0.f};

  f32x4 r0[4], r1[4], r2[4], r3[4];   // 4 named A sets (tile = 4 dwordx4)
  bf16x8 fa0, fa1;

#define SB __builtin_amdgcn_sched_barrier(0)
#define STAGE_B(kt, bufi)                                                     \
  {                                                                           \
    int kp_ = ((kt) + phase) & 63;                                            \
    _Pragma("unroll") for (int i = 0; i < 4; ++i)                             \
        __builtin_amdgcn_global_load_lds(                                     \
            (const __attribute__((address_space(1))) void*)(bSrc[i] + (size_t)kp_ * 64), \
            (__attribute__((address_space(3))) void*)&ldsB[bufi][(t + i * 512) * 8], \
            16, 0, 0);                                                        \
  }
#define LOAD_A(kt, rr)                                                        \
  {                                                                           \
    int kp_ = ((kt) + phase) & 63;                                            \
    const float* ap_ = aLane + (size_t)kp_ * 64;                              \
    rr[0] = *(const f32x4*)(ap_);                                             \
    rr[1] = *(const f32x4*)(ap_ + 4);                                         \
    rr[2] = *(const f32x4*)(ap_ + 32);                                        \
    rr[3] = *(const f32x4*)(ap_ + 36);                                        \
  }
#define CONV(rr)                                                              \
  {                                                                           \
    _Pragma("unroll") for (int e = 0; e < 4; ++e) {                           \
      fa0[e] = (short)f2bf(rr[0][e]); fa0[e + 4] = (short)f2bf(rr[1][e]);     \
      fa1[e] = (short)f2bf(rr[2][e]); fa1[e + 4] = (short)f2bf(rr[3][e]);     \
    }                                                                         \
  }
#define MFMAS(bufi)                                                           \
  {                                                                           \
    _Pragma("unroll") for (int ni = 0; ni < 16; ++ni) {                       \
      bf16x8 bv = *(const bf16x8*)(&ldsB[bufi][0] +                           \
                                   (ni * 16 + l15) * 64 + pos0);              \
      acc[ni] = __builtin_amdgcn_mfma_f32_16x16x32_bf16(fa0, bv, acc[ni],     \
                                                        0, 0, 0);             \
    }                                                                         \
    _Pragma("unroll") for (int ni = 0; ni < 16; ++ni) {                       \
      bf16x8 bv = *(const bf16x8*)(&ldsB[bufi][0] +                           \
                                   (ni * 16 + l15) * 64 + (pos0 ^ 32));      \
      acc[ni] = __builtin_amdgcn_mfma_f32_16x16x32_bf16(fa1, bv, acc[ni],     \
                                                        0, 0, 0);             \
    }                                                                         \
  }
// iter body: consume A set m (= kt%4) and buf m; stage B(kt+2)->buf (m+2)&3
#define BODY(m, kt, rr)                                                       \
  {                                                                           \
    CONV(rr);                   /* extract BEFORE reload */                   \
    SB;                                                                       \
    STAGE_B((kt) + 2, ((m) + 2) & 3);                                         \
    SB;                                                                       \
    LOAD_A((kt) + 4, rr);                                                     \
    SB;                                                                       \
    MFMAS(m);                                                                 \
    SB;                                                                       \
    asm volatile("s_waitcnt vmcnt(12)" ::: "memory");                         \
    SB;                                                                       \
    __builtin_amdgcn_s_barrier();                                             \
    SB;                                                                       \
  }

  // ---- prologue. Issue order sets the FIFO so that draining through A(1)
  // leaves exactly the steady-state tail {A(2), B(1), A(3)} = 12 instr.
  STAGE_B(0, 0);      // B(0)
  SB;
  LOAD_A(0, r0);
  SB;
  LOAD_A(1, r1);
  SB;
  LOAD_A(2, r2);
  SB;
  STAGE_B(1, 1);      // B(1)
  SB;
  LOAD_A(3, r3);
  SB;
  asm volatile("s_waitcnt vmcnt(12)" ::: "memory");  // B0,A0,A1 landed
  SB;
  __builtin_amdgcn_s_barrier();
  SB;

  // ---- main loop: 64 uniform iters, period-4 static roles
  for (int kt = 0; kt < 64; kt += 4) {
    BODY(0, kt, r0);
    BODY(1, kt + 1, r1);
    BODY(2, kt + 2, r2);
    BODY(3, kt + 3, r3);
  }

  // keep tail wrap prefetches live so the vmcnt FIFO accounting stays exact
  asm volatile("" ::"v"(r0[0][0]), "v"(r1[0][0]), "v"(r2[0][0]), "v"(r3[0][0]),
               "v"(r0[3][0]), "v"(r1[3][0]), "v"(r2[3][0]), "v"(r3[3][0]));

#undef SB
#undef STAGE_B
#undef LOAD_A
#undef CONV
#undef MFMAS
#undef BODY

  // C-write: wave wq owns q-rows qb+wq*16..+15; row=(l16*4+j), col=l15 per ni
  unsigned short* Ao = Amat + ((size_t)(batch * 4096 + qb + wq * 16)) * 256;
#pragma unroll
  for (int ni = 0; ni < 16; ++ni)
#pragma unroll
    for (int j = 0; j < 4; ++j)
      Ao[(size_t)(l16 * 4 + j) * 256 + ni * 16 + l15] = f2bf(acc[ni][j]);
}

// ---------------------------------------------------------------------------
// Kernel 3: out = x + alpha/4 * gathered conv_transpose contributions
// ---------------------------------------------------------------------------
__global__ __launch_bounds__(256) void epilogue_kernel(
    const float* __restrict__ x, const unsigned short* __restrict__ Amat,
    const float* __restrict__ alpha, float* __restrict__ out) {
  int b = blockIdx.x >> 7;
  int h = blockIdx.x & 127;
  int t = threadIdx.x;
  int w = t & 127;
  int cg = t >> 7;

  int ihi = (h + 1) >> 1, u_hi = (h + 1) & 1;
  int jhi = (w + 1) >> 1, v_hi = (w + 1) & 1;
  bool vi_hi = (ihi <= 63), vi_lo = (ihi >= 1);
  bool vj_hi = (jhi <= 63), vj_lo = (jhi >= 1);

  float al = alpha[0] * 0.25f;
  const unsigned short* Ab = Amat + (size_t)b * 4096 * 256;

#pragma unroll
  for (int cc = 0; cc < 8; ++cc) {
    int c = cg * 8 + cc;
    float s = 0.f;
    if (vi_hi) {
      const unsigned short* Ar = Ab + (size_t)(ihi * 64) * 256 + c * 16 + u_hi * 4;
      if (vj_hi) s += bf2f(Ar[jhi * 256 + v_hi]);
      if (vj_lo) s += bf2f(Ar[(jhi - 1) * 256 + v_hi + 2]);
    }
    if (vi_lo) {
      const unsigned short* Ar = Ab + (size_t)((ihi - 1) * 64) * 256 + c * 16 + (u_hi + 2) * 4;
      if (vj_hi) s += bf2f(Ar[jhi * 256 + v_hi]);
      if (vj_lo) s += bf2f(Ar[(jhi - 1) * 256 + v_hi + 2]);
    }
    size_t xi = (((size_t)b * 16 + c) * 128 + h) * 128 + w;
    out[xi] = x[xi] + al * s;
  }
}

extern "C" void kernel_launch(void* const* d_in, const int* in_sizes, int n_in,
                              void* d_out, int out_size, void* d_ws, size_t ws_size,
                              hipStream_t stream) {
  const float* x      = (const float*)d_in[0];
  const float* scores = (const float*)d_in[1];
  const float* alpha  = (const float*)d_in[2];
  float* out = (float*)d_out;

  unsigned short* vmatT = (unsigned short*)d_ws;
  unsigned short* Amat  = (unsigned short*)((char*)d_ws + (size_t)16 * 1024 * 1024);

  prep_vmat<<<4096, 256, 0, stream>>>(x, vmatT);
  gemm_scores_vmat<<<256, 512, 0, stream>>>(scores, vmatT, Amat);
  epilogue_kernel<<<1024, 256, 0, stream>>>(x, Amat, alpha, out);
}